// Round 5
// baseline (192.113 us; speedup 1.0000x reference)
//
#include <hip/hip_runtime.h>
#include <hip/hip_fp16.h>

// GCN, N=50000 nodes, E=800000 edges, 128->128(relu)->64, fp32 accum.
// CSR entries are 2B (src only).
// r15: EDGE-SPLIT x2 in both agg kernels to attack the serial gather
//   chain (avg degree 16 -> two dependent D=8 batches per 16-lane group
//   was the per-node critical path): 32 lanes/node = 2 edge-groups x 16
//   feature-lanes, alternate CSR entries (stride 2), partial sums merged
//   with one __shfl_xor(.,16) per accumulator. Halves the dependent-batch
//   count (avg 1 batch/group) and doubles gathers in flight. agg128 moves
//   to 512-thread blocks (16-node tile unchanged -> stage-B MFMA intact);
//   agg64 to 8 nodes/block x 6250 blocks. A/B test: latency-bound -> each
//   agg -25..35%; request-floor -> unchanged, pivot next round.
// r14 carry: separable norm (H1p/H2p pre-scaled by dis, folded pre-fp16-
//   rounding), CSR fill hidden under GEMM, W-prep rides count launch.
// r13 carry: 32-node gemm tiles, LDS-assembled full-line H1/H2 stores.
// r12 carry: swizzled fp16 W images, linear conflict-free W staging,
//   A-frags global->reg. NOTE (r10): degree-sorting bought ~0.

#define Nn 50000
#define Ne 800000
#define NE2 (Ne / 2)                  // 400000 int2 edge pairs
#define SCAN_B ((Nn + 1023) / 1024)   // 49 blocks
#define GT32 ((Nn + 31) / 32)         // 1563 gemm tiles (32 nodes)
#define E1B ((NE2 + 255) / 256)       // 1563 edge blocks (1 int2/thread)

using f16x8 = _Float16 __attribute__((ext_vector_type(8)));
using f32x4 = float __attribute__((ext_vector_type(4)));

// ---------------- count (+rank) + build swizzled fp16 W images ----------------
__global__ __launch_bounds__(256) void k_count_prep(
    const int2* __restrict__ col2, int* __restrict__ degi,
    ushort2* __restrict__ rank2, const float* __restrict__ W1,
    const float* __restrict__ W2, _Float16* __restrict__ W1h,
    _Float16* __restrict__ W2h) {
  const int b = blockIdx.x, t = threadIdx.x;
  if (b < E1B) {
    int i0 = b * 256 + t;
    if (i0 < NE2) {
      int2 c = col2[i0];
      ushort2 rk;
      rk.x = (unsigned short)atomicAdd(&degi[c.x], 1);
      rk.y = (unsigned short)atomicAdd(&degi[c.y], 1);
      rank2[i0] = rk;
    }
  } else if (b == E1B) {
    // W1: fp32 [k=128][c=128] -> W1h 2048 chunks, 8 per thread
    for (int i = 0; i < 8; ++i) {
      int id = i * 256 + t;
      int c = id & 127, k8 = id >> 7;
      f16x8 hv;
      #pragma unroll
      for (int j = 0; j < 8; ++j) hv[j] = (_Float16)W1[(k8 * 8 + j) * 128 + c];
      *(f16x8*)&W1h[c * 128 + ((k8 ^ (c & 7)) << 3)] = hv;
    }
  } else {
    // W2: fp32 [k=128][c=64] -> W2h 1024 chunks, 4 per thread
    for (int i = 0; i < 4; ++i) {
      int id = i * 256 + t;
      int c = id & 63, k8 = id >> 6;
      f16x8 hv;
      #pragma unroll
      for (int j = 0; j < 8; ++j) hv[j] = (_Float16)W2[(k8 * 8 + j) * 64 + c];
      *(f16x8*)&W2h[c * 128 + ((k8 ^ (c & 7)) << 3)] = hv;
    }
  }
}

// ---------------- scan phase 1: block-local exclusive scan + dis ----------------
__global__ __launch_bounds__(1024) void k_scan1(const int* __restrict__ degi,
                                                int* __restrict__ rowptr,
                                                float* __restrict__ dis,
                                                int* __restrict__ bsum) {
  __shared__ int wsum[16];
  int tid = threadIdx.x;
  int lane = tid & 63, wid = tid >> 6;
  int i = blockIdx.x * 1024 + tid;
  int v = (i < Nn) ? degi[i] : 0;
  if (i < Nn) dis[i] = rsqrtf((float)(v + 1));   // self-loop adds 1
  int incl = v;
  #pragma unroll
  for (int off = 1; off < 64; off <<= 1) {
    int t = __shfl_up(incl, off);
    if (lane >= off) incl += t;
  }
  if (lane == 63) wsum[wid] = incl;
  __syncthreads();
  if (wid == 0) {
    int wv = (lane < 16) ? wsum[lane] : 0;
    #pragma unroll
    for (int off = 1; off < 16; off <<= 1) {
      int t = __shfl_up(wv, off);
      if (lane >= off) wv += t;
    }
    if (lane < 16) wsum[lane] = wv;  // inclusive over wave totals
  }
  __syncthreads();
  int woff = (wid > 0) ? wsum[wid - 1] : 0;
  if (i < Nn) rowptr[i] = woff + incl - v;       // block-local exclusive
  if (tid == 0) bsum[blockIdx.x] = wsum[15];     // block total
}

// ---------------- scan phase 2+3 fused ----------------
__global__ __launch_bounds__(1024) void k_scan3(int* __restrict__ rowptr,
                                                const int* __restrict__ bsum) {
  __shared__ int off_s;
  int tid = threadIdx.x;
  if (tid < 64) {
    int v = (tid < SCAN_B) ? bsum[tid] : 0;
    int incl = v;
    #pragma unroll
    for (int off = 1; off < 64; off <<= 1) {
      int t = __shfl_up(incl, off);
      if (tid >= off) incl += t;
    }
    if (tid == (int)blockIdx.x) off_s = incl - v;          // exclusive offset
    if (blockIdx.x == 0 && tid == SCAN_B - 1) rowptr[Nn] = incl;  // == Ne
  }
  __syncthreads();
  int i = blockIdx.x * 1024 + tid;
  if (i < Nn) rowptr[i] += off_s;
}

// ---------------- FUSED: layer-1 MFMA GEMM (32-node tile, dis-scaled) + CSR fill ----------------
__global__ __launch_bounds__(256, 5) void k_gemm32_fill(
    const float* __restrict__ X, const _Float16* __restrict__ W1h,
    const float* __restrict__ dis, __half* __restrict__ H,
    const int2* __restrict__ row2, const int2* __restrict__ col2,
    const int* __restrict__ rowptr, const ushort2* __restrict__ rank2,
    unsigned short* __restrict__ csr) {
  __shared__ _Float16 Wts[128 * 128];   // 32 KB swizzled W image; reused for out
  _Float16* Hsx = Wts;                  // [32][136] fp16 out tile (8.7 KB)

  const int tid = threadIdx.x;
  const int base = blockIdx.x * 32;

  // stage W1h -> LDS: 2048 x 16B chunks, 8 per thread, fully coalesced
  {
    const f16x8* src = (const f16x8*)W1h;
    f16x8* dst = (f16x8*)Wts;
    #pragma unroll
    for (int i = 0; i < 8; ++i) dst[i * 256 + tid] = src[i * 256 + tid];
  }

  // CSR fill slice: 1 int2 per thread (needs rowptr+rank only)
  {
    int t = blockIdx.x * 256 + tid;
    if (t < NE2) {
      int2 r = row2[t];
      int2 c = col2[t];
      ushort2 k = rank2[t];
      csr[rowptr[c.x] + (int)k.x] = (unsigned short)r.x;
      csr[rowptr[c.y] + (int)k.y] = (unsigned short)r.y;
    }
  }

  // A-fragments direct from global X
  const int w = tid >> 6, lane = tid & 63;
  const int quad = lane >> 4, mrow = lane & 15;
  const int rbase = (w & 1) * 16, cbase = (w >> 1) * 64;
  int anode = base + rbase + mrow;
  if (anode >= Nn) anode = Nn - 1;
  const float4* xg = (const float4*)(X + (size_t)anode * 128);
  f16x8 av[4];
  #pragma unroll
  for (int ko = 0; ko < 4; ++ko) {
    float4 x0 = xg[ko * 8 + quad * 2];
    float4 x1 = xg[ko * 8 + quad * 2 + 1];
    av[ko][0] = (_Float16)x0.x; av[ko][1] = (_Float16)x0.y;
    av[ko][2] = (_Float16)x0.z; av[ko][3] = (_Float16)x0.w;
    av[ko][4] = (_Float16)x1.x; av[ko][5] = (_Float16)x1.y;
    av[ko][6] = (_Float16)x1.z; av[ko][7] = (_Float16)x1.w;
  }

  // dis for this lane's 4 output rows (folded into acc pre-rounding)
  float dv[4];
  #pragma unroll
  for (int r = 0; r < 4; ++r) {
    int node = base + rbase + quad * 4 + r;
    dv[r] = dis[(node < Nn) ? node : (Nn - 1)];
  }
  __syncthreads();

  f32x4 acc[4];
  #pragma unroll
  for (int ct = 0; ct < 4; ++ct) acc[ct] = (f32x4){0.f, 0.f, 0.f, 0.f};

  #pragma unroll
  for (int ko = 0; ko < 4; ++ko) {
    #pragma unroll
    for (int ct = 0; ct < 4; ++ct) {
      int c = cbase + ct * 16 + mrow;
      f16x8 bv = *(const f16x8*)&Wts[c * 128 + (((ko * 4 + quad) ^ (c & 7)) << 3)];
      acc[ct] = __builtin_amdgcn_mfma_f32_16x16x32_f16(av[ko], bv, acc[ct], 0, 0, 0);
    }
  }

  __syncthreads();   // all waves done reading Wts; safe to alias
  #pragma unroll
  for (int ct = 0; ct < 4; ++ct) {
    #pragma unroll
    for (int r = 0; r < 4; ++r)
      Hsx[(rbase + quad * 4 + r) * 136 + cbase + ct * 16 + mrow] =
          (_Float16)(acc[ct][r] * dv[r]);   // H1p = dis * (x@W1), one rounding
  }
  __syncthreads();

  // contiguous stores: 512 f16x8 chunks (32 rows x 16), 2 per thread
  #pragma unroll
  for (int i = 0; i < 2; ++i) {
    int id = i * 256 + tid;
    int r = id >> 4, ch = id & 15;
    int node = base + r;
    if (node < Nn)
      *(f16x8*)((_Float16*)H + (size_t)node * 128 + ch * 8) =
          *(const f16x8*)&Hsx[r * 136 + ch * 8];
  }
}

__device__ __forceinline__ float2 h2f(unsigned int u) {
  return __half22float2(*(const __half2*)&u);
}

// ---------------- FUSED: agg128(+b1, relu) -> LDS fp16 -> MFMA @ W2 -> H2p fp16 ----------------
// 512 threads, 16 nodes/block, 32 lanes/node = 2 edge-groups x 16 feat-lanes.
// Group eg handles CSR entries s+eg, s+eg+2, ... (stride 2); partial sums
// merged via __shfl_xor(.,16). Stage B (waves 0-3): 16x64 MFMA vs swizzled
// W2; stores H2p = dis*H2 (fp32 pre-round) as contiguous f16x8 chunks.
// Nn = 50000 = 3125 * 16 exactly -> no partial blocks.
__global__ __launch_bounds__(512) void k_agg128_gemm64(
    const __half* __restrict__ H, const unsigned short* __restrict__ csr,
    const int* __restrict__ rowptr, const float* __restrict__ dis,
    const float* __restrict__ bias, const _Float16* __restrict__ W2h,
    __half* __restrict__ H2, int n) {
  __shared__ _Float16 Wts[64 * 128];   // swizzled W2 image (16KB, linear copy)
  __shared__ _Float16 Hs[16 * 136];    // 16 aggregated rows; reused for out

  const int tid = threadIdx.x;

  // stage W2h -> LDS: 1024 x 16B chunks, 2 per thread, linear
  {
    const f16x8* src = (const f16x8*)W2h;
    f16x8* dst = (f16x8*)Wts;
    #pragma unroll
    for (int i = 0; i < 2; ++i) dst[i * 512 + tid] = src[i * 512 + tid];
  }

  const int nb = tid >> 5;                       // node-in-block [0,16)
  const int eg = (tid >> 4) & 1;                 // edge group {0,1}
  const int fl = tid & 15;                       // feature lane
  const int v = blockIdx.x * 16 + nb;

  // ---- stage A: sum H1p over this group's alternate neighbors ----
  int s = rowptr[v], e = rowptr[v + 1];
  float d = dis[v];
  const uint4* Hq = (const uint4*)H;             // 16 uint4 per 256B row
  float a0 = 0.f, a1 = 0.f, a2 = 0.f, a3 = 0.f;
  float a4 = 0.f, a5 = 0.f, a6 = 0.f, a7 = 0.f;
  if (eg == 0) {                                 // self row (unscaled) once
    uint4 hv = Hq[(size_t)v * 16 + fl];
    float2 p0 = h2f(hv.x), p1 = h2f(hv.y), p2 = h2f(hv.z), p3 = h2f(hv.w);
    a0 = p0.x; a1 = p0.y; a2 = p1.x; a3 = p1.y;
    a4 = p2.x; a5 = p2.y; a6 = p3.x; a7 = p3.y;
  }
  const int cnt = (e - s + 1 - eg) >> 1;         // this group's edge count
  const int pos = s + eg;                        // first idx (stride 2)
  constexpr int D = 8;
  if (cnt > 0) {
    int srcs[D];
    #pragma unroll
    for (int j = 0; j < D; ++j) {
      int idx = pos + 2 * j;
      srcs[j] = csr[(idx < e) ? idx : (e - 1)];
    }
    int done = 0;
    for (; done + D <= cnt; done += D) {         // full batches: plain adds
      uint4 q[D];
      #pragma unroll
      for (int j = 0; j < D; ++j) q[j] = Hq[(size_t)srcs[j] * 16 + fl];
      int ns[D];                                 // prefetch next batch srcs
      #pragma unroll
      for (int j = 0; j < D; ++j) {
        int idx = pos + 2 * (done + D + j);
        ns[j] = csr[(idx < e) ? idx : (e - 1)];
      }
      #pragma unroll
      for (int j = 0; j < D; ++j) {
        float2 t;
        t = h2f(q[j].x); a0 += t.x; a1 += t.y;
        t = h2f(q[j].y); a2 += t.x; a3 += t.y;
        t = h2f(q[j].z); a4 += t.x; a5 += t.y;
        t = h2f(q[j].w); a6 += t.x; a7 += t.y;
      }
      #pragma unroll
      for (int j = 0; j < D; ++j) srcs[j] = ns[j];
    }
    if (done < cnt) {                            // masked tail batch
      uint4 q[D];
      #pragma unroll
      for (int j = 0; j < D; ++j) q[j] = Hq[(size_t)srcs[j] * 16 + fl];
      #pragma unroll
      for (int j = 0; j < D; ++j) {
        float m = (done + j < cnt) ? 1.f : 0.f;
        float2 t;
        t = h2f(q[j].x); a0 = fmaf(m, t.x, a0); a1 = fmaf(m, t.y, a1);
        t = h2f(q[j].y); a2 = fmaf(m, t.x, a2); a3 = fmaf(m, t.y, a3);
        t = h2f(q[j].z); a4 = fmaf(m, t.x, a4); a5 = fmaf(m, t.y, a5);
        t = h2f(q[j].w); a6 = fmaf(m, t.x, a6); a7 = fmaf(m, t.y, a7);
      }
    }
  }
  // merge the two edge-groups (lanes l <-> l^16 hold same features)
  a0 += __shfl_xor(a0, 16); a1 += __shfl_xor(a1, 16);
  a2 += __shfl_xor(a2, 16); a3 += __shfl_xor(a3, 16);
  a4 += __shfl_xor(a4, 16); a5 += __shfl_xor(a5, 16);
  a6 += __shfl_xor(a6, 16); a7 += __shfl_xor(a7, 16);

  // row = relu(dis[v]*sum + b1), fp16 -> LDS row nb (group 0 writes)
  if (eg == 0) {
    const float4* Bq = (const float4*)bias;
    float4 b0 = Bq[fl * 2], b1v = Bq[fl * 2 + 1];
    f16x8 hrow;
    hrow[0] = (_Float16)fmaxf(fmaf(d, a0, b0.x), 0.f);
    hrow[1] = (_Float16)fmaxf(fmaf(d, a1, b0.y), 0.f);
    hrow[2] = (_Float16)fmaxf(fmaf(d, a2, b0.z), 0.f);
    hrow[3] = (_Float16)fmaxf(fmaf(d, a3, b0.w), 0.f);
    hrow[4] = (_Float16)fmaxf(fmaf(d, a4, b1v.x), 0.f);
    hrow[5] = (_Float16)fmaxf(fmaf(d, a5, b1v.y), 0.f);
    hrow[6] = (_Float16)fmaxf(fmaf(d, a6, b1v.z), 0.f);
    hrow[7] = (_Float16)fmaxf(fmaf(d, a7, b1v.w), 0.f);
    *(f16x8*)&Hs[nb * 136 + fl * 8] = hrow;
  }

  // ---- stage B on waves 0-3: 16x64 = (16x128) @ (128x64) ----
  const int wid = tid >> 6, lane = tid & 63;
  const int quad = lane >> 4, mrow = lane & 15;
  float dst4[4];
  if (wid < 4) {
    #pragma unroll
    for (int r = 0; r < 4; ++r)
      dst4[r] = dis[blockIdx.x * 16 + quad * 4 + r];
  }
  __syncthreads();

  f32x4 acc = (f32x4){0.f, 0.f, 0.f, 0.f};
  if (wid < 4) {
    const int c = wid * 16 + mrow;
    #pragma unroll
    for (int ko = 0; ko < 4; ++ko) {
      f16x8 avx = *(const f16x8*)&Hs[mrow * 136 + ko * 32 + quad * 8];
      f16x8 bv = *(const f16x8*)&Wts[c * 128 + (((ko * 4 + quad) ^ (c & 7)) << 3)];
      acc = __builtin_amdgcn_mfma_f32_16x16x32_f16(avx, bv, acc, 0, 0, 0);
    }
  }
  __syncthreads();   // all waves done reading Hs; safe to alias
  if (wid < 4) {
    #pragma unroll
    for (int r = 0; r < 4; ++r)
      Hs[(quad * 4 + r) * 136 + wid * 16 + mrow] =
          (_Float16)(acc[r] * dst4[r]);          // H2p = dis * H2, one rounding
  }
  __syncthreads();

  // contiguous stores: 128 f16x8 chunks (16 rows x 8), threads 0..127
  if (tid < 128) {
    int r = tid >> 3, ch = tid & 7;
    *(f16x8*)((_Float16*)H2 + ((size_t)blockIdx.x * 16 + r) * 64 + ch * 8) =
        *(const f16x8*)&Hs[r * 136 + ch * 8];
  }
}

// ---------------- aggregate 64 feats: out = dis[v]*sum(H2p) + b2 ----------------
// 8 nodes/block, 32 lanes/node = 2 edge-groups x 16 feat-lanes (uint2/lane),
// stride-2 CSR split, shfl_xor(16) merge. 50000 = 6250 * 8 exactly.
__global__ __launch_bounds__(256) void k_agg64(const __half* __restrict__ H,
                                               const unsigned short* __restrict__ csr,
                                               const int* __restrict__ rowptr,
                                               const float* __restrict__ dis,
                                               const float* __restrict__ bias,
                                               float* __restrict__ Out, int n) {
  const int tid = threadIdx.x;
  const int nb = tid >> 5;                       // node-in-block [0,8)
  const int eg = (tid >> 4) & 1;
  const int fl = tid & 15;
  const int v = blockIdx.x * 8 + nb;
  int s = rowptr[v], e = rowptr[v + 1];
  float d = dis[v];
  const uint2* Hq = (const uint2*)H;             // 16 uint2 per 128B row
  float a0 = 0.f, a1 = 0.f, a2 = 0.f, a3 = 0.f;
  if (eg == 0) {                                 // self row once
    uint2 hv = Hq[(size_t)v * 16 + fl];
    float2 p0 = h2f(hv.x), p1 = h2f(hv.y);
    a0 = p0.x; a1 = p0.y; a2 = p1.x; a3 = p1.y;
  }
  const int cnt = (e - s + 1 - eg) >> 1;
  const int pos = s + eg;
  constexpr int D = 8;
  if (cnt > 0) {
    int srcs[D];
    #pragma unroll
    for (int j = 0; j < D; ++j) {
      int idx = pos + 2 * j;
      srcs[j] = csr[(idx < e) ? idx : (e - 1)];
    }
    int done = 0;
    for (; done + D <= cnt; done += D) {         // full batches: plain adds
      uint2 q[D];
      #pragma unroll
      for (int j = 0; j < D; ++j) q[j] = Hq[(size_t)srcs[j] * 16 + fl];
      int ns[D];
      #pragma unroll
      for (int j = 0; j < D; ++j) {
        int idx = pos + 2 * (done + D + j);
        ns[j] = csr[(idx < e) ? idx : (e - 1)];
      }
      #pragma unroll
      for (int j = 0; j < D; ++j) {
        float2 t;
        t = h2f(q[j].x); a0 += t.x; a1 += t.y;
        t = h2f(q[j].y); a2 += t.x; a3 += t.y;
      }
      #pragma unroll
      for (int j = 0; j < D; ++j) srcs[j] = ns[j];
    }
    if (done < cnt) {                            // masked tail batch
      uint2 q[D];
      #pragma unroll
      for (int j = 0; j < D; ++j) q[j] = Hq[(size_t)srcs[j] * 16 + fl];
      #pragma unroll
      for (int j = 0; j < D; ++j) {
        float m = (done + j < cnt) ? 1.f : 0.f;
        float2 t;
        t = h2f(q[j].x); a0 = fmaf(m, t.x, a0); a1 = fmaf(m, t.y, a1);
        t = h2f(q[j].y); a2 = fmaf(m, t.x, a2); a3 = fmaf(m, t.y, a3);
      }
    }
  }
  a0 += __shfl_xor(a0, 16); a1 += __shfl_xor(a1, 16);
  a2 += __shfl_xor(a2, 16); a3 += __shfl_xor(a3, 16);
  if (eg == 0) {
    const float4* Bq = (const float4*)bias;
    float4 b = Bq[fl];
    float4 o = make_float4(fmaf(d, a0, b.x), fmaf(d, a1, b.y),
                           fmaf(d, a2, b.z), fmaf(d, a3, b.w));
    ((float4*)(Out + (size_t)v * 64))[fl] = o;
  }
}

extern "C" void kernel_launch(void* const* d_in, const int* in_sizes, int n_in,
                              void* d_out, int out_size, void* d_ws, size_t ws_size,
                              hipStream_t stream) {
  const float* x  = (const float*)d_in[0];
  const int*   ei = (const int*)d_in[1];    // [2, E] row-major
  const int*   row = ei;                    // edge_index[0] (source)
  const int*   col = ei + Ne;               // edge_index[1] (dest / segment)
  const float* W1 = (const float*)d_in[2];
  const float* b1 = (const float*)d_in[3];
  const float* W2 = (const float*)d_in[4];
  const float* b2 = (const float*)d_in[5];
  float* out = (float*)d_out;

  char* ws = (char*)d_ws;
  size_t off = 0;
  auto alloc = [&](size_t bytes) -> void* {
    void* p = ws + off;
    off += (bytes + 255) & ~(size_t)255;
    return p;
  };
  int*    degi   = (int*)   alloc(Nn * sizeof(int));
  int*    rowptr = (int*)   alloc((Nn + 1) * sizeof(int));
  float*  dis    = (float*) alloc(Nn * sizeof(float));
  int*    bsum   = (int*)   alloc(64 * sizeof(int));
  unsigned short* rank = (unsigned short*)alloc((size_t)Ne * sizeof(unsigned short)); // 1.6 MB
  unsigned short* csr  = (unsigned short*)alloc((size_t)Ne * sizeof(unsigned short)); // 1.6 MB
  __half* H1     = (__half*)alloc((size_t)Nn * 128 * sizeof(__half));  // 12.8 MB (pre-scaled)
  __half* H2     = (__half*)alloc((size_t)Nn * 64 * sizeof(__half));   // 6.4 MB (pre-scaled)
  _Float16* W1h  = (_Float16*)alloc(128 * 128 * sizeof(_Float16));     // 32 KB
  _Float16* W2h  = (_Float16*)alloc(64 * 128 * sizeof(_Float16));      // 16 KB

  const int NGB = (Nn + 15) / 16;           // 3125 agg128 blocks (16 nodes)
  const int NGB8 = (Nn + 7) / 8;            // 6250 agg64 blocks (8 nodes)

  hipMemsetAsync(degi, 0, Nn * sizeof(int), stream);

  // count (+rank) + W images (count must precede scan; W blocks ride along)
  k_count_prep<<<E1B + 2, 256, 0, stream>>>((const int2*)col, degi,
                                            (ushort2*)rank, W1, W2, W1h, W2h);
  k_scan1<<<SCAN_B, 1024, 0, stream>>>(degi, rowptr, dis, bsum);
  k_scan3<<<SCAN_B, 1024, 0, stream>>>(rowptr, bsum);
  // fused: H1p = fp16(dis * (x@W1)) + CSR fill (hidden under GEMM)
  k_gemm32_fill<<<GT32, 256, 0, stream>>>(x, W1h, dis, H1, (const int2*)row,
                                          (const int2*)col, rowptr,
                                          (const ushort2*)rank, csr);
  // fused: H2p = fp16( dis * (relu(dis*sum(H1p) + b1) @ W2) )
  k_agg128_gemm64<<<NGB, 512, 0, stream>>>(H1, csr, rowptr, dis, b1, W2h, H2, Nn);
  // layer 2: out = dis * sum(H2p) + b2
  k_agg64<<<NGB8, 256, 0, stream>>>(H2, csr, rowptr, dis, b2, out, Nn);
}